// Round 7
// baseline (403.577 us; speedup 1.0000x reference)
//
#include <hip/hip_runtime.h>
#include <hip/hip_fp16.h>

#define BATCH   4
#define SEQ     2048
#define DM      1024
#define HEADS   16
#define HD      64
#define M_TOK   (BATCH * SEQ)   // 8192
#define QK_LD   2048            // merged Q|K projection leading dim

// 0.125 (1/sqrt(64)) * log2(e): folded into Wq so logits come out in log2 units.
#define QSCALE  0.1803368801111204f

typedef __attribute__((ext_vector_type(8)))  _Float16 half8;
typedef __attribute__((ext_vector_type(4)))  float    f32x4;
typedef __attribute__((ext_vector_type(16))) float    f32x16;

__device__ __forceinline__ unsigned short f2h(float x) {
    return __half_as_ushort(__float2half(x));
}
__device__ __forceinline__ float h2f(unsigned short u) {
    return __half2float(__ushort_as_half(u));
}
// v_exp_f32 IS exp2 on gfx9xx.
__device__ __forceinline__ float fast_exp2(float x) {
    float r; asm volatile("v_exp_f32 %0, %1" : "=v"(r) : "v"(x)); return r;
}
// pack two f32 -> f16x2 in one VGPR (v_cvt_pkrtz_f16_f32), a in [15:0].
__device__ __forceinline__ unsigned int pk2(float a, float b) {
    __fp16 __attribute__((ext_vector_type(2))) h =
        __builtin_amdgcn_cvt_pkrtz(a, b);
    return __builtin_bit_cast(unsigned int, h);
}
// async global->LDS DMA, 16B per lane; LDS dest = uniform base + lane*16.
__device__ __forceinline__ void dma16(const void* g, void* l) {
    __builtin_amdgcn_global_load_lds(
        (const __attribute__((address_space(1))) void*)g,
        (__attribute__((address_space(3))) void*)l, 16, 0, 0);
}

// ---------------------------------------------------------------------------
// x -> hi/lo f16 split (elementwise)
// ---------------------------------------------------------------------------
__global__ __launch_bounds__(256) void split_cast(
    const float* __restrict__ x, unsigned short* __restrict__ hi,
    unsigned short* __restrict__ lo)
{
    const int i = (blockIdx.x * 256 + threadIdx.x) * 8;
    float4 a = *(const float4*)(x + i);
    float4 b = *(const float4*)(x + i + 4);
    float v[8] = {a.x, a.y, a.z, a.w, b.x, b.y, b.z, b.w};
    unsigned short hb[8], lb[8];
#pragma unroll
    for (int j = 0; j < 8; ++j) {
        hb[j] = f2h(v[j]);
        lb[j] = f2h(v[j] - h2f(hb[j]));
    }
    *(float4*)(hi + i) = *(float4*)hb;
    *(float4*)(lo + i) = *(float4*)lb;
}

// ---------------------------------------------------------------------------
// Weight transpose (+scale, +optional split): W[K][N] f32 -> Wt[N][K] f16
// ---------------------------------------------------------------------------
template<int SPLIT>
__global__ __launch_bounds__(256) void wtrans(
    const float* __restrict__ W, unsigned short* __restrict__ Th_out,
    unsigned short* __restrict__ Tl_out, float scale)
{
    __shared__ unsigned short Th[64][72];
    __shared__ unsigned short Tl[SPLIT ? 64 : 1][72];
    const int t  = threadIdx.x;
    const int n0 = blockIdx.x * 64, k0 = blockIdx.y * 64;
    const int kr = t >> 2, cg = (t & 3) << 4;
#pragma unroll
    for (int jj = 0; jj < 16; jj += 4) {
        float4 wv = *(const float4*)(W + (size_t)(k0 + kr) * DM + n0 + cg + jj);
        float vv[4] = {wv.x, wv.y, wv.z, wv.w};
#pragma unroll
        for (int j = 0; j < 4; ++j) {
            float v = vv[j] * scale;
            unsigned short h = f2h(v);
            Th[cg + jj + j][kr] = h;
            if (SPLIT) Tl[cg + jj + j][kr] = f2h(v - h2f(h));
        }
    }
    __syncthreads();
    const int nr = t >> 2, kg = (t & 3) << 4;
    size_t go = (size_t)(n0 + nr) * DM + k0 + kg;
    *(float4*)(Th_out + go)     = *(float4*)&Th[nr][kg];
    *(float4*)(Th_out + go + 8) = *(float4*)&Th[nr][kg + 8];
    if (SPLIT) {
        *(float4*)(Tl_out + go)     = *(float4*)&Tl[nr][kg];
        *(float4*)(Tl_out + go + 8) = *(float4*)&Tl[nr][kg + 8];
    }
}

// ---------------------------------------------------------------------------
// f16 MFMA GEMM: C = A[M,K] @ Bt[N,K]^T, 128x128 tile, BK=32.
// ASYNC PIPELINE: double-buffered LDS, ONE barrier per iter; the barrier's
// vmcnt(0) drain IS the wait for the prefetch issued a full compute-phase
// earlier (iter it stages it+1 right after the barrier, then computes it).
// PASSES: 1 = plain; 3 = hi/lo split (A*B + A*Bl + Al*B) fp32-grade.
// EPI: 0 = f32 out; 1 = split-f16 out; 2 = f16 out; 3 = transposed-V f16.
// R5: 1D grid + bijective XCD-chunked swizzle (T1) so blocks sharing A/B
// panels land on the same XCD's L2 (grid %8==0 for all uses). [kept]
// ---------------------------------------------------------------------------
template<int PASSES, int EPI>
__global__ __launch_bounds__(256, 2) void gemm_f16(
    const unsigned short* __restrict__ Ah, const unsigned short* __restrict__ Al,
    const unsigned short* __restrict__ Bh, const unsigned short* __restrict__ Bl,
    void* __restrict__ O0, void* __restrict__ O1, int M, int N, int K)
{
    __shared__ unsigned short As_h[2][128 * 32];
    __shared__ unsigned short Bs_h[2][128 * 32];
    __shared__ unsigned short As_l[PASSES == 3 ? 2 : 1][PASSES == 3 ? 128 * 32 : 16];
    __shared__ unsigned short Bs_l[PASSES == 3 ? 2 : 1][PASSES == 3 ? 128 * 32 : 16];

    const int t = threadIdx.x;
    const int w = t >> 6, lane = t & 63, quad = lane >> 4, l15 = lane & 15;
    const int wm = w >> 1, wn = w & 1;

    // XCD-chunked bijective swizzle: xcd = lin&7 owns gridDim/8 CONSECUTIVE
    // remapped ids -> neighboring tiles (shared A/B panels) share one L2.
    const int lin = blockIdx.x;
    const int cpx = gridDim.x >> 3;                  // grid %8 == 0 always
    const int swz = (lin & 7) * cpx + (lin >> 3);
    const int nbx = N >> 7;                          // N/128 tiles along x
    const int m0 = (swz / nbx) * 128, n0 = (swz % nbx) * 128;

    const int drow = w * 32 + (lane >> 2);
    const int dcol = (lane & 3) * 8;

    auto stage = [&](int buf, int k0) {
#pragma unroll
        for (int inst = 0; inst < 2; ++inst) {
            const size_t ga = (size_t)(m0 + drow + inst * 16) * K + k0 + dcol;
            const size_t gb = (size_t)(n0 + drow + inst * 16) * K + k0 + dcol;
            const int lo = (w * 32 + inst * 16) * 32;
            dma16(Ah + ga, &As_h[buf][lo]);
            dma16(Bh + gb, &Bs_h[buf][lo]);
            if (PASSES == 3) {
                dma16(Al + ga, &As_l[buf][lo]);
                dma16(Bl + gb, &Bs_l[buf][lo]);
            }
        }
    };

    f32x4 acc[4][4];
#pragma unroll
    for (int mt = 0; mt < 4; ++mt)
#pragma unroll
        for (int nt = 0; nt < 4; ++nt)
#pragma unroll
            for (int r = 0; r < 4; ++r) acc[mt][nt][r] = 0.f;

    const int NIT = K >> 5;
    stage(0, 0);
    for (int it = 0; it < NIT; ++it) {
        __syncthreads();   // drains vmcnt -> buf[cur] ready; prior cur^1 reads done
        const int cur = it & 1;
        if (it + 1 < NIT) stage(cur ^ 1, (it + 1) * 32);

        half8 aH[4], bH[4], aL[4], bL[4];
#pragma unroll
        for (int mt = 0; mt < 4; ++mt) {
            const int row = wm * 64 + mt * 16 + l15;
            aH[mt] = *(const half8*)&As_h[cur][row * 32 + quad * 8];
            if (PASSES == 3) aL[mt] = *(const half8*)&As_l[cur][row * 32 + quad * 8];
        }
#pragma unroll
        for (int nt = 0; nt < 4; ++nt) {
            const int row = wn * 64 + nt * 16 + l15;
            bH[nt] = *(const half8*)&Bs_h[cur][row * 32 + quad * 8];
            if (PASSES == 3) bL[nt] = *(const half8*)&Bs_l[cur][row * 32 + quad * 8];
        }
#pragma unroll
        for (int mt = 0; mt < 4; ++mt)
#pragma unroll
            for (int nt = 0; nt < 4; ++nt) {
                acc[mt][nt] = __builtin_amdgcn_mfma_f32_16x16x32_f16(
                    aH[mt], bH[nt], acc[mt][nt], 0, 0, 0);
                if (PASSES == 3) {
                    acc[mt][nt] = __builtin_amdgcn_mfma_f32_16x16x32_f16(
                        aH[mt], bL[nt], acc[mt][nt], 0, 0, 0);
                    acc[mt][nt] = __builtin_amdgcn_mfma_f32_16x16x32_f16(
                        aL[mt], bH[nt], acc[mt][nt], 0, 0, 0);
                }
            }
    }

    // Epilogue. C/D layout: col = lane&15, row = quad*4 + reg.
#pragma unroll
    for (int mt = 0; mt < 4; ++mt)
#pragma unroll
        for (int nt = 0; nt < 4; ++nt) {
            const int row0 = m0 + wm * 64 + mt * 16 + quad * 4;
            const int col  = n0 + wn * 64 + nt * 16 + l15;
            if (EPI == 0) {
#pragma unroll
                for (int r = 0; r < 4; ++r)
                    ((float*)O0)[(size_t)(row0 + r) * N + col] = acc[mt][nt][r];
            } else if (EPI == 1) {
#pragma unroll
                for (int r = 0; r < 4; ++r) {
                    float v = acc[mt][nt][r];
                    unsigned short h = f2h(v);
                    ((unsigned short*)O0)[(size_t)(row0 + r) * N + col] = h;
                    ((unsigned short*)O1)[(size_t)(row0 + r) * N + col] =
                        f2h(v - h2f(h));
                }
            } else if (EPI == 2) {
#pragma unroll
                for (int r = 0; r < 4; ++r)
                    ((unsigned short*)O0)[(size_t)(row0 + r) * N + col] =
                        f2h(acc[mt][nt][r]);
            } else {  // EPI == 3: Vt[b][h][d][s]; regs are consecutive s
                const int b = row0 >> 11, s = row0 & 2047;
                const int hh = col >> 6, d = col & 63;
                unsigned short vs[4];
#pragma unroll
                for (int r = 0; r < 4; ++r) vs[r] = f2h(acc[mt][nt][r]);
                *(ushort4*)((unsigned short*)O0 +
                            (((size_t)(b * HEADS + hh)) * HD + d) * SEQ + s) =
                    *(ushort4*)vs;
            }
        }
}

// ---------------------------------------------------------------------------
// 32x32x16 MFMA flash attention, async-pipelined. R7 RESTRUCTURE:
// R6 lesson: K-loop cost (staging DMA + frag reads) is PER-BLOCK, so more
// blocks = more total K/V traffic (R6: conflicts exactly 2x, dur +10us).
// R5 lesson: attn is latency-bound (FETCH 213->41MB changed nothing); true
// per-SIMD matrix-pipe busy ~9%; only 2 waves/SIMD were resident.
// R7: same 512-block / 256-row-q-tile geometry as R5 (staging volume
// UNCHANGED), but 512-thread blocks = 8 waves, each wave owns ONE 32-row
// q-set (qs dim dropped). 2 blocks/CU -> 16 waves/CU = 4 waves/SIMD:
// double the independent-wave pool hiding MFMA chains, softmax chains and
// barrier drains. Cost: K/V frag reads double (LDS pipe ~25% busy - has
// headroom); staging split 8 ways (1 dma-triple/wave). VGPR ~88 < 128 cap
// for 4 waves/EU; LDS 48KB x 2 = 96KB/CU.
// Block = (b, h, 256-row Q tile), 8 waves. K(hi,lo), V^T double-buffered in
// LDS via global_load_lds, XOR swizzle (chunk ^= row&7) on unpadded [64][64]
// tiles. ONE barrier per iter. Per-lane online softmax in log2 units;
// in-register P transform; PV as O^T = V^T.P^T. XCD-chunked block swizzle.
// ---------------------------------------------------------------------------
__global__ __launch_bounds__(512, 4) void attn_f16(
    const unsigned short* __restrict__ QKh,   // [M_TOK][2048]: Q | K  (hi)
    const unsigned short* __restrict__ QKl,   // [M_TOK][2048]: Q | K  (lo)
    const unsigned short* __restrict__ Vt,    // [b][h][d][s]
    unsigned short* __restrict__ Oc)          // [b][s][h*64+d] f16
{
    __shared__ unsigned short SM[2][3 * 4096];  // per buf: Kh | Kl | V^T, 8 KB each

    const int t = threadIdx.x;
    const int w = t >> 6, lane = t & 63;        // w = 0..7
    const int g = lane >> 5, l31 = lane & 31;

    // XCD-chunked bijective swizzle over the 512-block grid (8 q, 16 h, 4 b).
    // xcd = lin&7 gets 64 consecutive swz ids (q fastest) = 8 complete
    // (h,b) K/V-sharing groups on one XCD.
    const int lin = blockIdx.x + 8 * blockIdx.y + 128 * blockIdx.z;  // 0..511
    const int swz = (lin & 7) * 64 + (lin >> 3);
    const int b = swz >> 7, h = (swz >> 3) & 15, q0 = (swz & 7) * 256;

    const size_t row0   = (size_t)b * SEQ;
    const size_t qcol   = (size_t)h * HD;          // Q cols [h*64, h*64+64)
    const size_t kcol   = 1024 + qcol;             // K cols
    const size_t vtbase = ((size_t)(b * HEADS + h)) * HD * SEQ;

    // DMA per-lane invariants: lane l -> row_local = l>>3, swizzled chunk.
    const int rl  = lane >> 3;                       // 0..7
    const int sw8 = ((lane & 7) ^ (rl & 7)) * 8;     // element offset in row
    const int x7  = l31 & 7;                         // frag-read swizzle key

    // 8 waves x 1 dma-triple: wave w stages rows [w*8, w*8+8) of the 64-row
    // K/V tiles (64 lanes x 16B = 8 rows x 128B per dma16).
    auto stage = [&](int buf, int k0) {
        const int r8 = w * 8;
        const size_t gk = (row0 + k0 + r8 + rl) * QK_LD + kcol + sw8;
        const int lo = r8 * 64;
        dma16(QKh + gk, &SM[buf][lo]);
        dma16(QKl + gk, &SM[buf][4096 + lo]);
        const size_t gv = vtbase + (size_t)(r8 + rl) * SEQ + k0 + sw8;
        dma16(Vt + gv, &SM[buf][8192 + lo]);
    };

    // Q B-frags direct from global: lane n = q-row, k(d) = ks*16 + g*8 + j.
    half8 bQh[4], bQl[4];
    {
        const size_t qr = (row0 + q0 + w * 32 + l31) * QK_LD + qcol;
#pragma unroll
        for (int ks = 0; ks < 4; ++ks) {
            bQh[ks] = *(const half8*)(QKh + qr + ks * 16 + g * 8);
            bQl[ks] = *(const half8*)(QKl + qr + ks * 16 + g * 8);
        }
    }

    f32x16 o_acc[2];
#pragma unroll
    for (int mt = 0; mt < 2; ++mt)
#pragma unroll
        for (int r = 0; r < 16; ++r) o_acc[mt][r] = 0.f;
    float m_r = -3.0e38f, l_r = 0.f;

    stage(0, 0);
    const int NIT = SEQ / 64;
    for (int it = 0; it < NIT; ++it) {
        __syncthreads();   // drains vmcnt -> buf[cur] ready; cur^1 reads done
        const int cur = it & 1;
        if (it + 1 < NIT) stage(cur ^ 1, (it + 1) * 64);
        const unsigned short* Ks  = &SM[cur][0];
        const unsigned short* Ksl = &SM[cur][4096];
        const unsigned short* Vs  = &SM[cur][8192];

        // S^T = K.Q^T: M = 64 keys (2 tiles), k = d (4 steps), 3-pass split
        f32x16 s[2];
#pragma unroll
        for (int kt = 0; kt < 2; ++kt)
#pragma unroll
            for (int r = 0; r < 16; ++r) s[kt][r] = 0.f;
#pragma unroll
        for (int kt = 0; kt < 2; ++kt)
#pragma unroll
            for (int ks = 0; ks < 4; ++ks) {
                const int off = (kt * 32 + l31) * 64 + (((ks * 2 + g) ^ x7) * 8);
                half8 aKh = *(const half8*)&Ks[off];
                half8 aKl = *(const half8*)&Ksl[off];
                s[kt] = __builtin_amdgcn_mfma_f32_32x32x16_f16(
                    aKh, bQh[ks], s[kt], 0, 0, 0);
                s[kt] = __builtin_amdgcn_mfma_f32_32x32x16_f16(
                    aKl, bQh[ks], s[kt], 0, 0, 0);
                s[kt] = __builtin_amdgcn_mfma_f32_32x32x16_f16(
                    aKh, bQl[ks], s[kt], 0, 0, 0);
            }

        // Per-lane online softmax (lane's q-row; holds 32 of 64 keys)
        float mx = s[0][0];
#pragma unroll
        for (int kt = 0; kt < 2; ++kt)
#pragma unroll
            for (int r = 0; r < 16; ++r) mx = fmaxf(mx, s[kt][r]);
        mx = fmaxf(mx, __shfl_xor(mx, 32));
        const float nm = fmaxf(m_r, mx);
        const float al = fast_exp2(m_r - nm);
        m_r = nm;
        float rs = 0.f;
#pragma unroll
        for (int kt = 0; kt < 2; ++kt)
#pragma unroll
            for (int r = 0; r < 16; ++r) {
                float pv = fast_exp2(s[kt][r] - nm);
                s[kt][r] = pv;
                rs += pv;
            }
        rs += __shfl_xor(rs, 32);
        l_r = l_r * al + rs;
#pragma unroll
        for (int mt = 0; mt < 2; ++mt)
#pragma unroll
            for (int r = 0; r < 16; ++r) o_acc[mt][r] *= al;

        // P: C-layout -> PV operand layout, in registers (reg-quad swap
        // between lane pairs l <-> l^32).
        half8 bP[4];
#pragma unroll
        for (int kt = 0; kt < 2; ++kt)
#pragma unroll
            for (int ksl = 0; ksl < 2; ++ksl) {
                const int base = ksl * 8;
                unsigned int lo0 = pk2(s[kt][base + 0], s[kt][base + 1]);
                unsigned int lo1 = pk2(s[kt][base + 2], s[kt][base + 3]);
                unsigned int hi0 = pk2(s[kt][base + 4], s[kt][base + 5]);
                unsigned int hi1 = pk2(s[kt][base + 6], s[kt][base + 7]);
                unsigned int s0 = g ? lo0 : hi0;
                unsigned int s1 = g ? lo1 : hi1;
                unsigned int r0 = (unsigned int)__shfl_xor((int)s0, 32);
                unsigned int r1 = (unsigned int)__shfl_xor((int)s1, 32);
                union { unsigned int u[4]; half8 hv; } u;
                u.u[0] = g ? r0 : lo0;
                u.u[1] = g ? r1 : lo1;
                u.u[2] = g ? hi0 : r0;
                u.u[3] = g ? hi1 : r1;
                bP[kt * 2 + ksl] = u.hv;
            }

        // O^T += V^T . P^T : M = d (2 tiles), k = key (4 steps)
#pragma unroll
        for (int mt = 0; mt < 2; ++mt)
#pragma unroll
            for (int kk = 0; kk < 4; ++kk) {
                const int off = (mt * 32 + l31) * 64 + (((kk * 2 + g) ^ x7) * 8);
                half8 aV = *(const half8*)&Vs[off];
                o_acc[mt] = __builtin_amdgcn_mfma_f32_32x32x16_f16(
                    aV, bP[kk], o_acc[mt], 0, 0, 0);
            }
    }

    // Epilogue: O^T col = own q-row; rows d = (r&3)+8*(r>>2)+4g+32mt.
    {
        const float inv = 1.0f / l_r;
        unsigned short* orow =
            Oc + (row0 + q0 + w * 32 + l31) * DM + h * HD;
#pragma unroll
        for (int mt = 0; mt < 2; ++mt)
#pragma unroll
            for (int rq = 0; rq < 4; ++rq) {
                unsigned int w0 = pk2(o_acc[mt][rq * 4 + 0] * inv,
                                      o_acc[mt][rq * 4 + 1] * inv);
                unsigned int w1 = pk2(o_acc[mt][rq * 4 + 2] * inv,
                                      o_acc[mt][rq * 4 + 3] * inv);
                const int d0 = mt * 32 + rq * 8 + g * 4;
                uint2 pkd; pkd.x = w0; pkd.y = w1;
                *(uint2*)(orow + d0) = pkd;
            }
    }
}

// ---------------------------------------------------------------------------
extern "C" void kernel_launch(void* const* d_in, const int* in_sizes, int n_in,
                              void* d_out, int out_size, void* d_ws, size_t ws_size,
                              hipStream_t stream) {
    const float* x  = (const float*)d_in[0];
    const float* Wq = (const float*)d_in[1];
    const float* Wk = (const float*)d_in[2];
    const float* Wv = (const float*)d_in[3];
    const float* Wo = (const float*)d_in[4];
    float* out = (float*)d_out;

    char* ws = (char*)d_ws;
    const size_t SZ_TOK = (size_t)M_TOK * DM * 2;  // 16 MB f16 token matrix
    const size_t SZ_W   = (size_t)DM * DM * 2;     // 2 MB

    unsigned short* xh     = (unsigned short*)(ws);
    unsigned short* xl     = (unsigned short*)(ws + SZ_TOK);
    unsigned short* Wqkt_h = (unsigned short*)(ws + 2 * SZ_TOK);            // 4 MB
    unsigned short* Wqkt_l = (unsigned short*)(ws + 2 * SZ_TOK + 2 * SZ_W); // 4 MB
    unsigned short* Wvt    = (unsigned short*)(ws + 2 * SZ_TOK + 4 * SZ_W);
    unsigned short* Wot    = (unsigned short*)(ws + 2 * SZ_TOK + 5 * SZ_W);
    unsigned short* QKh    = (unsigned short*)(ws + 2 * SZ_TOK + 6 * SZ_W); // 32 MB
    unsigned short* QKl    = (unsigned short*)(ws + 4 * SZ_TOK + 6 * SZ_W); // 32 MB
    unsigned short* Vt_    = (unsigned short*)(ws + 6 * SZ_TOK + 6 * SZ_W); // 16 MB
    unsigned short* concat = xh;  // x dead after V projection

    dim3 blk(256);

    hipLaunchKernelGGL(split_cast, dim3(M_TOK * DM / (256 * 8)), blk, 0, stream,
                       x, xh, xl);
    dim3 wgrid(DM / 64, DM / 64);
    hipLaunchKernelGGL((wtrans<1>), wgrid, blk, 0, stream, Wq, Wqkt_h, Wqkt_l,
                       QSCALE);
    hipLaunchKernelGGL((wtrans<1>), wgrid, blk, 0, stream, Wk,
                       Wqkt_h + (size_t)DM * DM, Wqkt_l + (size_t)DM * DM, 1.0f);
    hipLaunchKernelGGL((wtrans<0>), wgrid, blk, 0, stream, Wv, Wvt, nullptr, 1.0f);
    hipLaunchKernelGGL((wtrans<0>), wgrid, blk, 0, stream, Wo, Wot, nullptr, 1.0f);

    // Merged Q|K projection: N = 2048, 3-pass split in, split out. 1D grid
    // (16*64 = 1024 blocks, %8==0) with in-kernel XCD-chunked swizzle.
    hipLaunchKernelGGL((gemm_f16<3, 1>), dim3((QK_LD / 128) * (M_TOK / 128)),
                       blk, 0, stream,
                       xh, xl, Wqkt_h, Wqkt_l, QKh, QKl, M_TOK, QK_LD, DM);
    hipLaunchKernelGGL((gemm_f16<1, 3>), dim3((DM / 128) * (M_TOK / 128)),
                       blk, 0, stream,
                       xh, nullptr, Wvt, nullptr, Vt_, nullptr, M_TOK, DM, DM);

    dim3 agrid(SEQ / 256, HEADS, BATCH);  // 8 x 16 x 4 = 512 blocks
    hipLaunchKernelGGL(attn_f16, agrid, dim3(512), 0, stream,
                       QKh, QKl, Vt_, concat);

    hipLaunchKernelGGL((gemm_f16<1, 0>), dim3((DM / 128) * (M_TOK / 128)),
                       blk, 0, stream,
                       concat, nullptr, Wot, nullptr, out, nullptr, M_TOK, DM, DM);
}

// Round 8
// 388.709 us; speedup vs baseline: 1.0383x; 1.0383x over previous
//
#include <hip/hip_runtime.h>
#include <hip/hip_fp16.h>

#define BATCH   4
#define SEQ     2048
#define DM      1024
#define HEADS   16
#define HD      64
#define M_TOK   (BATCH * SEQ)   // 8192
#define QK_LD   2048            // merged Q|K projection leading dim

// 0.125 (1/sqrt(64)) * log2(e): folded into Wq so logits come out in log2 units.
#define QSCALE  0.1803368801111204f

typedef __attribute__((ext_vector_type(8)))  _Float16 half8;
typedef __attribute__((ext_vector_type(4)))  float    f32x4;
typedef __attribute__((ext_vector_type(16))) float    f32x16;

__device__ __forceinline__ unsigned short f2h(float x) {
    return __half_as_ushort(__float2half(x));
}
__device__ __forceinline__ float h2f(unsigned short u) {
    return __half2float(__ushort_as_half(u));
}
// v_exp_f32 IS exp2 on gfx9xx.
__device__ __forceinline__ float fast_exp2(float x) {
    float r; asm volatile("v_exp_f32 %0, %1" : "=v"(r) : "v"(x)); return r;
}
// pack two f32 -> f16x2 in one VGPR (v_cvt_pkrtz_f16_f32), a in [15:0].
__device__ __forceinline__ unsigned int pk2(float a, float b) {
    __fp16 __attribute__((ext_vector_type(2))) h =
        __builtin_amdgcn_cvt_pkrtz(a, b);
    return __builtin_bit_cast(unsigned int, h);
}
// async global->LDS DMA, 16B per lane; LDS dest = uniform base + lane*16.
__device__ __forceinline__ void dma16(const void* g, void* l) {
    __builtin_amdgcn_global_load_lds(
        (const __attribute__((address_space(1))) void*)g,
        (__attribute__((address_space(3))) void*)l, 16, 0, 0);
}

// ---------------------------------------------------------------------------
// x -> hi/lo f16 split (elementwise)
// ---------------------------------------------------------------------------
__global__ __launch_bounds__(256) void split_cast(
    const float* __restrict__ x, unsigned short* __restrict__ hi,
    unsigned short* __restrict__ lo)
{
    const int i = (blockIdx.x * 256 + threadIdx.x) * 8;
    float4 a = *(const float4*)(x + i);
    float4 b = *(const float4*)(x + i + 4);
    float v[8] = {a.x, a.y, a.z, a.w, b.x, b.y, b.z, b.w};
    unsigned short hb[8], lb[8];
#pragma unroll
    for (int j = 0; j < 8; ++j) {
        hb[j] = f2h(v[j]);
        lb[j] = f2h(v[j] - h2f(hb[j]));
    }
    *(float4*)(hi + i) = *(float4*)hb;
    *(float4*)(lo + i) = *(float4*)lb;
}

// ---------------------------------------------------------------------------
// Weight transpose (+scale, +optional split): W[K][N] f32 -> Wt[N][K] f16
// ---------------------------------------------------------------------------
template<int SPLIT>
__global__ __launch_bounds__(256) void wtrans(
    const float* __restrict__ W, unsigned short* __restrict__ Th_out,
    unsigned short* __restrict__ Tl_out, float scale)
{
    __shared__ unsigned short Th[64][72];
    __shared__ unsigned short Tl[SPLIT ? 64 : 1][72];
    const int t  = threadIdx.x;
    const int n0 = blockIdx.x * 64, k0 = blockIdx.y * 64;
    const int kr = t >> 2, cg = (t & 3) << 4;
#pragma unroll
    for (int jj = 0; jj < 16; jj += 4) {
        float4 wv = *(const float4*)(W + (size_t)(k0 + kr) * DM + n0 + cg + jj);
        float vv[4] = {wv.x, wv.y, wv.z, wv.w};
#pragma unroll
        for (int j = 0; j < 4; ++j) {
            float v = vv[j] * scale;
            unsigned short h = f2h(v);
            Th[cg + jj + j][kr] = h;
            if (SPLIT) Tl[cg + jj + j][kr] = f2h(v - h2f(h));
        }
    }
    __syncthreads();
    const int nr = t >> 2, kg = (t & 3) << 4;
    size_t go = (size_t)(n0 + nr) * DM + k0 + kg;
    *(float4*)(Th_out + go)     = *(float4*)&Th[nr][kg];
    *(float4*)(Th_out + go + 8) = *(float4*)&Th[nr][kg + 8];
    if (SPLIT) {
        *(float4*)(Tl_out + go)     = *(float4*)&Tl[nr][kg];
        *(float4*)(Tl_out + go + 8) = *(float4*)&Tl[nr][kg + 8];
    }
}

// ---------------------------------------------------------------------------
// f16 MFMA GEMM: C = A[M,K] @ Bt[N,K]^T, 128x128 tile, BK=32.
// ASYNC PIPELINE: double-buffered LDS, ONE barrier per iter; the barrier's
// vmcnt(0) drain IS the wait for the prefetch issued a full compute-phase
// earlier (iter it stages it+1 right after the barrier, then computes it).
// PASSES: 1 = plain; 3 = hi/lo split (A*B + A*Bl + Al*B) fp32-grade.
// EPI: 0 = f32 out; 1 = split-f16 out; 2 = f16 out; 3 = transposed-V f16.
// R5: 1D grid + bijective XCD-chunked swizzle (T1) so blocks sharing A/B
// panels land on the same XCD's L2 (grid %8==0 for all uses). [kept]
// ---------------------------------------------------------------------------
template<int PASSES, int EPI>
__global__ __launch_bounds__(256, 2) void gemm_f16(
    const unsigned short* __restrict__ Ah, const unsigned short* __restrict__ Al,
    const unsigned short* __restrict__ Bh, const unsigned short* __restrict__ Bl,
    void* __restrict__ O0, void* __restrict__ O1, int M, int N, int K)
{
    __shared__ unsigned short As_h[2][128 * 32];
    __shared__ unsigned short Bs_h[2][128 * 32];
    __shared__ unsigned short As_l[PASSES == 3 ? 2 : 1][PASSES == 3 ? 128 * 32 : 16];
    __shared__ unsigned short Bs_l[PASSES == 3 ? 2 : 1][PASSES == 3 ? 128 * 32 : 16];

    const int t = threadIdx.x;
    const int w = t >> 6, lane = t & 63, quad = lane >> 4, l15 = lane & 15;
    const int wm = w >> 1, wn = w & 1;

    // XCD-chunked bijective swizzle: xcd = lin&7 owns gridDim/8 CONSECUTIVE
    // remapped ids -> neighboring tiles (shared A/B panels) share one L2.
    const int lin = blockIdx.x;
    const int cpx = gridDim.x >> 3;                  // grid %8 == 0 always
    const int swz = (lin & 7) * cpx + (lin >> 3);
    const int nbx = N >> 7;                          // N/128 tiles along x
    const int m0 = (swz / nbx) * 128, n0 = (swz % nbx) * 128;

    const int drow = w * 32 + (lane >> 2);
    const int dcol = (lane & 3) * 8;

    auto stage = [&](int buf, int k0) {
#pragma unroll
        for (int inst = 0; inst < 2; ++inst) {
            const size_t ga = (size_t)(m0 + drow + inst * 16) * K + k0 + dcol;
            const size_t gb = (size_t)(n0 + drow + inst * 16) * K + k0 + dcol;
            const int lo = (w * 32 + inst * 16) * 32;
            dma16(Ah + ga, &As_h[buf][lo]);
            dma16(Bh + gb, &Bs_h[buf][lo]);
            if (PASSES == 3) {
                dma16(Al + ga, &As_l[buf][lo]);
                dma16(Bl + gb, &Bs_l[buf][lo]);
            }
        }
    };

    f32x4 acc[4][4];
#pragma unroll
    for (int mt = 0; mt < 4; ++mt)
#pragma unroll
        for (int nt = 0; nt < 4; ++nt)
#pragma unroll
            for (int r = 0; r < 4; ++r) acc[mt][nt][r] = 0.f;

    const int NIT = K >> 5;
    stage(0, 0);
    for (int it = 0; it < NIT; ++it) {
        __syncthreads();   // drains vmcnt -> buf[cur] ready; prior cur^1 reads done
        const int cur = it & 1;
        if (it + 1 < NIT) stage(cur ^ 1, (it + 1) * 32);

        half8 aH[4], bH[4], aL[4], bL[4];
#pragma unroll
        for (int mt = 0; mt < 4; ++mt) {
            const int row = wm * 64 + mt * 16 + l15;
            aH[mt] = *(const half8*)&As_h[cur][row * 32 + quad * 8];
            if (PASSES == 3) aL[mt] = *(const half8*)&As_l[cur][row * 32 + quad * 8];
        }
#pragma unroll
        for (int nt = 0; nt < 4; ++nt) {
            const int row = wn * 64 + nt * 16 + l15;
            bH[nt] = *(const half8*)&Bs_h[cur][row * 32 + quad * 8];
            if (PASSES == 3) bL[nt] = *(const half8*)&Bs_l[cur][row * 32 + quad * 8];
        }
#pragma unroll
        for (int mt = 0; mt < 4; ++mt)
#pragma unroll
            for (int nt = 0; nt < 4; ++nt) {
                acc[mt][nt] = __builtin_amdgcn_mfma_f32_16x16x32_f16(
                    aH[mt], bH[nt], acc[mt][nt], 0, 0, 0);
                if (PASSES == 3) {
                    acc[mt][nt] = __builtin_amdgcn_mfma_f32_16x16x32_f16(
                        aH[mt], bL[nt], acc[mt][nt], 0, 0, 0);
                    acc[mt][nt] = __builtin_amdgcn_mfma_f32_16x16x32_f16(
                        aL[mt], bH[nt], acc[mt][nt], 0, 0, 0);
                }
            }
    }

    // Epilogue. C/D layout: col = lane&15, row = quad*4 + reg.
#pragma unroll
    for (int mt = 0; mt < 4; ++mt)
#pragma unroll
        for (int nt = 0; nt < 4; ++nt) {
            const int row0 = m0 + wm * 64 + mt * 16 + quad * 4;
            const int col  = n0 + wn * 64 + nt * 16 + l15;
            if (EPI == 0) {
#pragma unroll
                for (int r = 0; r < 4; ++r)
                    ((float*)O0)[(size_t)(row0 + r) * N + col] = acc[mt][nt][r];
            } else if (EPI == 1) {
#pragma unroll
                for (int r = 0; r < 4; ++r) {
                    float v = acc[mt][nt][r];
                    unsigned short h = f2h(v);
                    ((unsigned short*)O0)[(size_t)(row0 + r) * N + col] = h;
                    ((unsigned short*)O1)[(size_t)(row0 + r) * N + col] =
                        f2h(v - h2f(h));
                }
            } else if (EPI == 2) {
#pragma unroll
                for (int r = 0; r < 4; ++r)
                    ((unsigned short*)O0)[(size_t)(row0 + r) * N + col] =
                        f2h(acc[mt][nt][r]);
            } else {  // EPI == 3: Vt[b][h][d][s]; regs are consecutive s
                const int b = row0 >> 11, s = row0 & 2047;
                const int hh = col >> 6, d = col & 63;
                unsigned short vs[4];
#pragma unroll
                for (int r = 0; r < 4; ++r) vs[r] = f2h(acc[mt][nt][r]);
                *(ushort4*)((unsigned short*)O0 +
                            (((size_t)(b * HEADS + hh)) * HD + d) * SEQ + s) =
                    *(ushort4*)vs;
            }
        }
}

// ---------------------------------------------------------------------------
// 32x32x16 MFMA flash attention, async-pipelined. R7 structure (KEPT):
// 512 blocks x 512 threads (8 waves), wave owns ONE 32-row q-set; 2 blocks/
// CU = 4 waves/SIMD (occupancy 18.6->35.7, attn 150->142.5us). K(hi,lo),
// V^T double-buffered in LDS via global_load_lds, XOR swizzle (chunk ^=
// row&7) on unpadded [64][64] tiles. ONE barrier per iter. Per-lane online
// softmax in log2 units; in-register P transform; PV as O^T = V^T.P^T.
// XCD-chunked block swizzle (FETCH 213->41MB, R5).
//
// R8 (two catalog techniques, distinct counter signatures):
//  - T13 defer-max, THR=8 log2-units: skip alpha-exp, l-rescale and the 32
//    o_acc mults (critical-path VALU between softmax and PV) whenever
//    __all(mx <= m_r + 8). P <= 2^8 = 256, f16-safe; division by l_r
//    normalizes identically. Signature: VALUBusy down ~5.
//  - T5 s_setprio(1) around QK and PV MFMA clusters: with 2 desynced
//    blocks/CU x 8 waves there is per-iter phase diversity for the CU
//    scheduler to arbitrate (m191 regime). Signature: MfmaUtil up ~3.
// ---------------------------------------------------------------------------
__global__ __launch_bounds__(512, 4) void attn_f16(
    const unsigned short* __restrict__ QKh,   // [M_TOK][2048]: Q | K  (hi)
    const unsigned short* __restrict__ QKl,   // [M_TOK][2048]: Q | K  (lo)
    const unsigned short* __restrict__ Vt,    // [b][h][d][s]
    unsigned short* __restrict__ Oc)          // [b][s][h*64+d] f16
{
    __shared__ unsigned short SM[2][3 * 4096];  // per buf: Kh | Kl | V^T, 8 KB each

    const int t = threadIdx.x;
    const int w = t >> 6, lane = t & 63;        // w = 0..7
    const int g = lane >> 5, l31 = lane & 31;

    // XCD-chunked bijective swizzle over the 512-block grid (8 q, 16 h, 4 b).
    const int lin = blockIdx.x + 8 * blockIdx.y + 128 * blockIdx.z;  // 0..511
    const int swz = (lin & 7) * 64 + (lin >> 3);
    const int b = swz >> 7, h = (swz >> 3) & 15, q0 = (swz & 7) * 256;

    const size_t row0   = (size_t)b * SEQ;
    const size_t qcol   = (size_t)h * HD;          // Q cols [h*64, h*64+64)
    const size_t kcol   = 1024 + qcol;             // K cols
    const size_t vtbase = ((size_t)(b * HEADS + h)) * HD * SEQ;

    // DMA per-lane invariants: lane l -> row_local = l>>3, swizzled chunk.
    const int rl  = lane >> 3;                       // 0..7
    const int sw8 = ((lane & 7) ^ (rl & 7)) * 8;     // element offset in row
    const int x7  = l31 & 7;                         // frag-read swizzle key

    // 8 waves x 1 dma-triple: wave w stages rows [w*8, w*8+8) of the 64-row
    // K/V tiles (64 lanes x 16B = 8 rows x 128B per dma16).
    auto stage = [&](int buf, int k0) {
        const int r8 = w * 8;
        const size_t gk = (row0 + k0 + r8 + rl) * QK_LD + kcol + sw8;
        const int lo = r8 * 64;
        dma16(QKh + gk, &SM[buf][lo]);
        dma16(QKl + gk, &SM[buf][4096 + lo]);
        const size_t gv = vtbase + (size_t)(r8 + rl) * SEQ + k0 + sw8;
        dma16(Vt + gv, &SM[buf][8192 + lo]);
    };

    // Q B-frags direct from global: lane n = q-row, k(d) = ks*16 + g*8 + j.
    half8 bQh[4], bQl[4];
    {
        const size_t qr = (row0 + q0 + w * 32 + l31) * QK_LD + qcol;
#pragma unroll
        for (int ks = 0; ks < 4; ++ks) {
            bQh[ks] = *(const half8*)(QKh + qr + ks * 16 + g * 8);
            bQl[ks] = *(const half8*)(QKl + qr + ks * 16 + g * 8);
        }
    }

    f32x16 o_acc[2];
#pragma unroll
    for (int mt = 0; mt < 2; ++mt)
#pragma unroll
        for (int r = 0; r < 16; ++r) o_acc[mt][r] = 0.f;
    float m_r = -3.0e38f, l_r = 0.f;

    stage(0, 0);
    const int NIT = SEQ / 64;
    for (int it = 0; it < NIT; ++it) {
        __syncthreads();   // drains vmcnt -> buf[cur] ready; cur^1 reads done
        const int cur = it & 1;
        if (it + 1 < NIT) stage(cur ^ 1, (it + 1) * 64);
        const unsigned short* Ks  = &SM[cur][0];
        const unsigned short* Ksl = &SM[cur][4096];
        const unsigned short* Vs  = &SM[cur][8192];

        // S^T = K.Q^T: M = 64 keys (2 tiles), k = d (4 steps), 3-pass split
        f32x16 s[2];
#pragma unroll
        for (int kt = 0; kt < 2; ++kt)
#pragma unroll
            for (int r = 0; r < 16; ++r) s[kt][r] = 0.f;
        __builtin_amdgcn_s_setprio(1);
#pragma unroll
        for (int kt = 0; kt < 2; ++kt)
#pragma unroll
            for (int ks = 0; ks < 4; ++ks) {
                const int off = (kt * 32 + l31) * 64 + (((ks * 2 + g) ^ x7) * 8);
                half8 aKh = *(const half8*)&Ks[off];
                half8 aKl = *(const half8*)&Ksl[off];
                s[kt] = __builtin_amdgcn_mfma_f32_32x32x16_f16(
                    aKh, bQh[ks], s[kt], 0, 0, 0);
                s[kt] = __builtin_amdgcn_mfma_f32_32x32x16_f16(
                    aKl, bQh[ks], s[kt], 0, 0, 0);
                s[kt] = __builtin_amdgcn_mfma_f32_32x32x16_f16(
                    aKh, bQl[ks], s[kt], 0, 0, 0);
            }
        __builtin_amdgcn_s_setprio(0);

        // Per-lane online softmax (lane's q-row; holds 32 of 64 keys)
        float mx = s[0][0];
#pragma unroll
        for (int kt = 0; kt < 2; ++kt)
#pragma unroll
            for (int r = 0; r < 16; ++r) mx = fmaxf(mx, s[kt][r]);
        mx = fmaxf(mx, __shfl_xor(mx, 32));

        // T13 defer-max: rescale only when the tile max grew > THR=8.
        // Logits are log2-units; deferred P bounded by 2^8 = 256 (f16-safe);
        // l_r accumulates at the same stale m_r, so P/l_r is unchanged.
        if (!__all(mx <= m_r + 8.f)) {
            const float nm = fmaxf(m_r, mx);
            const float al = fast_exp2(m_r - nm);
            m_r = nm;
            l_r *= al;
#pragma unroll
            for (int mt = 0; mt < 2; ++mt)
#pragma unroll
                for (int r = 0; r < 16; ++r) o_acc[mt][r] *= al;
        }
        float rs = 0.f;
#pragma unroll
        for (int kt = 0; kt < 2; ++kt)
#pragma unroll
            for (int r = 0; r < 16; ++r) {
                float pv = fast_exp2(s[kt][r] - m_r);
                s[kt][r] = pv;
                rs += pv;
            }
        rs += __shfl_xor(rs, 32);
        l_r += rs;

        // P: C-layout -> PV operand layout, in registers (reg-quad swap
        // between lane pairs l <-> l^32).
        half8 bP[4];
#pragma unroll
        for (int kt = 0; kt < 2; ++kt)
#pragma unroll
            for (int ksl = 0; ksl < 2; ++ksl) {
                const int base = ksl * 8;
                unsigned int lo0 = pk2(s[kt][base + 0], s[kt][base + 1]);
                unsigned int lo1 = pk2(s[kt][base + 2], s[kt][base + 3]);
                unsigned int hi0 = pk2(s[kt][base + 4], s[kt][base + 5]);
                unsigned int hi1 = pk2(s[kt][base + 6], s[kt][base + 7]);
                unsigned int s0 = g ? lo0 : hi0;
                unsigned int s1 = g ? lo1 : hi1;
                unsigned int r0 = (unsigned int)__shfl_xor((int)s0, 32);
                unsigned int r1 = (unsigned int)__shfl_xor((int)s1, 32);
                union { unsigned int u[4]; half8 hv; } u;
                u.u[0] = g ? r0 : lo0;
                u.u[1] = g ? r1 : lo1;
                u.u[2] = g ? hi0 : r0;
                u.u[3] = g ? hi1 : r1;
                bP[kt * 2 + ksl] = u.hv;
            }

        // O^T += V^T . P^T : M = d (2 tiles), k = key (4 steps)
        __builtin_amdgcn_s_setprio(1);
#pragma unroll
        for (int mt = 0; mt < 2; ++mt)
#pragma unroll
            for (int kk = 0; kk < 4; ++kk) {
                const int off = (mt * 32 + l31) * 64 + (((kk * 2 + g) ^ x7) * 8);
                half8 aV = *(const half8*)&Vs[off];
                o_acc[mt] = __builtin_amdgcn_mfma_f32_32x32x16_f16(
                    aV, bP[kk], o_acc[mt], 0, 0, 0);
            }
        __builtin_amdgcn_s_setprio(0);
    }

    // Epilogue: O^T col = own q-row; rows d = (r&3)+8*(r>>2)+4g+32mt.
    {
        const float inv = 1.0f / l_r;
        unsigned short* orow =
            Oc + (row0 + q0 + w * 32 + l31) * DM + h * HD;
#pragma unroll
        for (int mt = 0; mt < 2; ++mt)
#pragma unroll
            for (int rq = 0; rq < 4; ++rq) {
                unsigned int w0 = pk2(o_acc[mt][rq * 4 + 0] * inv,
                                      o_acc[mt][rq * 4 + 1] * inv);
                unsigned int w1 = pk2(o_acc[mt][rq * 4 + 2] * inv,
                                      o_acc[mt][rq * 4 + 3] * inv);
                const int d0 = mt * 32 + rq * 8 + g * 4;
                uint2 pkd; pkd.x = w0; pkd.y = w1;
                *(uint2*)(orow + d0) = pkd;
            }
    }
}

// ---------------------------------------------------------------------------
extern "C" void kernel_launch(void* const* d_in, const int* in_sizes, int n_in,
                              void* d_out, int out_size, void* d_ws, size_t ws_size,
                              hipStream_t stream) {
    const float* x  = (const float*)d_in[0];
    const float* Wq = (const float*)d_in[1];
    const float* Wk = (const float*)d_in[2];
    const float* Wv = (const float*)d_in[3];
    const float* Wo = (const float*)d_in[4];
    float* out = (float*)d_out;

    char* ws = (char*)d_ws;
    const size_t SZ_TOK = (size_t)M_TOK * DM * 2;  // 16 MB f16 token matrix
    const size_t SZ_W   = (size_t)DM * DM * 2;     // 2 MB

    unsigned short* xh     = (unsigned short*)(ws);
    unsigned short* xl     = (unsigned short*)(ws + SZ_TOK);
    unsigned short* Wqkt_h = (unsigned short*)(ws + 2 * SZ_TOK);            // 4 MB
    unsigned short* Wqkt_l = (unsigned short*)(ws + 2 * SZ_TOK + 2 * SZ_W); // 4 MB
    unsigned short* Wvt    = (unsigned short*)(ws + 2 * SZ_TOK + 4 * SZ_W);
    unsigned short* Wot    = (unsigned short*)(ws + 2 * SZ_TOK + 5 * SZ_W);
    unsigned short* QKh    = (unsigned short*)(ws + 2 * SZ_TOK + 6 * SZ_W); // 32 MB
    unsigned short* QKl    = (unsigned short*)(ws + 4 * SZ_TOK + 6 * SZ_W); // 32 MB
    unsigned short* Vt_    = (unsigned short*)(ws + 6 * SZ_TOK + 6 * SZ_W); // 16 MB
    unsigned short* concat = xh;  // x dead after V projection

    dim3 blk(256);

    hipLaunchKernelGGL(split_cast, dim3(M_TOK * DM / (256 * 8)), blk, 0, stream,
                       x, xh, xl);
    dim3 wgrid(DM / 64, DM / 64);
    hipLaunchKernelGGL((wtrans<1>), wgrid, blk, 0, stream, Wq, Wqkt_h, Wqkt_l,
                       QSCALE);
    hipLaunchKernelGGL((wtrans<1>), wgrid, blk, 0, stream, Wk,
                       Wqkt_h + (size_t)DM * DM, Wqkt_l + (size_t)DM * DM, 1.0f);
    hipLaunchKernelGGL((wtrans<0>), wgrid, blk, 0, stream, Wv, Wvt, nullptr, 1.0f);
    hipLaunchKernelGGL((wtrans<0>), wgrid, blk, 0, stream, Wo, Wot, nullptr, 1.0f);

    // Merged Q|K projection: N = 2048, 3-pass split in, split out. 1D grid
    // (16*64 = 1024 blocks, %8==0) with in-kernel XCD-chunked swizzle.
    hipLaunchKernelGGL((gemm_f16<3, 1>), dim3((QK_LD / 128) * (M_TOK / 128)),
                       blk, 0, stream,
                       xh, xl, Wqkt_h, Wqkt_l, QKh, QKl, M_TOK, QK_LD, DM);
    hipLaunchKernelGGL((gemm_f16<1, 3>), dim3((DM / 128) * (M_TOK / 128)),
                       blk, 0, stream,
                       xh, nullptr, Wvt, nullptr, Vt_, nullptr, M_TOK, DM, DM);

    dim3 agrid(SEQ / 256, HEADS, BATCH);  // 8 x 16 x 4 = 512 blocks
    hipLaunchKernelGGL(attn_f16, agrid, dim3(512), 0, stream,
                       QKh, QKl, Vt_, concat);

    hipLaunchKernelGGL((gemm_f16<1, 0>), dim3((DM / 128) * (M_TOK / 128)),
                       blk, 0, stream,
                       concat, nullptr, Wot, nullptr, out, nullptr, M_TOK, DM, DM);
}